// Round 7
// baseline (263.276 us; speedup 1.0000x reference)
//
#include <hip/hip_runtime.h>
#include <math.h>

#define BB 8
#define TT 100
#define PP 1000
#define NJ 52      // V regs per thread in k4 (50 real j, 2 pad)
#define GROW 56    // G row stride floats (224B, 16B aligned)
#define HSTRIDE 68 // h_all row stride floats (272B, 16B aligned)

// ws layout (floats):
//   xk : [800][256] at 0        (204800)
//   XcT: [56][1000] at 204800   (56000)
//   G  : [800][56]  at 260800   (44800)

// ---------------- K1: xk[bt][j] = bias[j] + sum_k xt[bt][k]*kern[k][j] -----------------
// 400 blocks x 2 rows; depth-1 prefetch of the 8 kern loads so the next k-group's
// loads are in flight during this group's FMAs (round-6 had no cross-iter prefetch).
__global__ __launch_bounds__(256) void k1_xk(const int* __restrict__ pro_id,
    const int* __restrict__ label, const float* __restrict__ X,
    const float* __restrict__ onehot, const float* __restrict__ kern,
    const float* __restrict__ bias, float* __restrict__ xk)
{
    __shared__ __align__(16) float xt[2][256];
    const int j = threadIdx.x;
    const int r0 = blockIdx.x * 2;
#pragma unroll
    for (int r = 0; r < 2; ++r) {
        int pid = pro_id[r0 + r];
        int lab = label[r0 + r];
        xt[r][j] = X[pid * 128 + (j & 127)] * onehot[lab * 256 + j];
    }
    __syncthreads();
    float acc0 = bias[j], acc1 = acc0;
    float kc[8];
#pragma unroll
    for (int i = 0; i < 8; ++i) kc[i] = kern[i * 256 + j];
    for (int kg = 0; kg < 32; ++kg) {
        float kn[8];
        const int kgn = (kg < 31) ? kg + 1 : 31;
#pragma unroll
        for (int i = 0; i < 8; ++i) kn[i] = kern[(kgn * 8 + i) * 256 + j];
        const int k0 = kg * 8;
        float4 xa0 = *(const float4*)&xt[0][k0];
        float4 xa1 = *(const float4*)&xt[0][k0 + 4];
        float4 xb0 = *(const float4*)&xt[1][k0];
        float4 xb1 = *(const float4*)&xt[1][k0 + 4];
        acc0 += xa0.x * kc[0] + xa0.y * kc[1] + xa0.z * kc[2] + xa0.w * kc[3]
              + xa1.x * kc[4] + xa1.y * kc[5] + xa1.z * kc[6] + xa1.w * kc[7];
        acc1 += xb0.x * kc[0] + xb0.y * kc[1] + xb0.z * kc[2] + xb0.w * kc[3]
              + xb1.x * kc[4] + xb1.y * kc[5] + xb1.z * kc[6] + xb1.w * kc[7];
#pragma unroll
        for (int i = 0; i < 8; ++i) kc[i] = kn[i];
    }
    xk[(r0 + 0) * 256 + j] = acc0;
    xk[(r0 + 1) * 256 + j] = acc1;
}

// ---------------- MID: blocks 0..7 = LSTM, blocks 8..23 = XcT (k3) ---------------------
// LSTM v3: ONE WAVE per batch, lane u owns unit u (all 4 gates), rec in ~256 VGPRs.
// NO __syncthreads in the recurrence -> no vmcnt(0) drain at a barrier (round-6's
// 1630 cyc/step was the xk prefetch being force-drained by the per-step barrier).
// h broadcast via wave-synchronous LDS (same-wave DS in-order + lgkmcnt wait).
__global__ __launch_bounds__(256, 1) void mid(const float* __restrict__ xk,
    const float* __restrict__ rec, const float* __restrict__ W1,
    const float* __restrict__ X, const float* __restrict__ b1,
    float* __restrict__ G, float* __restrict__ XcT)
{
    __shared__ __align__(16) float smem[14720];  // 58.9 KB union
    const int tid = threadIdx.x;

    if (blockIdx.x < 8) {
        float* h_all = smem;                      // [101][68] = 27.5 KB
        float* w1s   = smem + (TT + 1) * HSTRIDE; // [64][52]  = 13.3 KB
        const int b = blockIdx.x;

        // all 256 threads stage W1 for the G tail
        for (int idx = tid; idx < 3200; idx += 256) {
            int u2 = idx / 50, jj = idx - u2 * 50;
            w1s[u2 * 52 + jj] = W1[idx];
        }
        if (tid < 64) h_all[tid] = 0.f;           // h(-1) = 0
        __syncthreads();

        if (tid < 64) {                           // wave 0 only: the recurrence
            const int u = tid;
            const float* xkb = xk + b * TT * 256;
            float2 rif[64], rgo[64];              // rec columns: ~256 VGPRs
#pragma unroll
            for (int u2 = 0; u2 < 64; ++u2) {
                const float* rr = rec + u2 * 256;
                rif[u2] = make_float2(rr[u], rr[64 + u]);
                rgo[u2] = make_float2(rr[128 + u], rr[192 + u]);
            }
            float c = 0.f;
            // 3-deep xk pipeline (loads stay in flight: no barrier to drain them)
            float2 aif = make_float2(xkb[u], xkb[64 + u]);
            float2 ago = make_float2(xkb[128 + u], xkb[192 + u]);
            float2 bif = make_float2(xkb[256 + u], xkb[256 + 64 + u]);
            float2 bgo = make_float2(xkb[256 + 128 + u], xkb[256 + 192 + u]);
            float2 cif = make_float2(xkb[512 + u], xkb[512 + 64 + u]);
            float2 cgo = make_float2(xkb[512 + 128 + u], xkb[512 + 192 + u]);

            for (int t = 0; t < TT; ++t) {
                float2 zif = aif, zgo = ago;
                aif = bif; ago = bgo; bif = cif; bgo = cgo;
                int tn = (t + 3 < TT) ? t + 3 : TT - 1;
                const float* xp = xkb + tn * 256;
                cif = make_float2(xp[u], xp[64 + u]);
                cgo = make_float2(xp[128 + u], xp[192 + u]);

                const float4* h4p = (const float4*)&h_all[t * HSTRIDE];
#pragma unroll
                for (int m = 0; m < 16; ++m) {
                    float4 h4 = h4p[m];           // broadcast ds_read_b128
                    zif.x += h4.x * rif[4 * m + 0].x; zif.y += h4.x * rif[4 * m + 0].y;
                    zgo.x += h4.x * rgo[4 * m + 0].x; zgo.y += h4.x * rgo[4 * m + 0].y;
                    zif.x += h4.y * rif[4 * m + 1].x; zif.y += h4.y * rif[4 * m + 1].y;
                    zgo.x += h4.y * rgo[4 * m + 1].x; zgo.y += h4.y * rgo[4 * m + 1].y;
                    zif.x += h4.z * rif[4 * m + 2].x; zif.y += h4.z * rif[4 * m + 2].y;
                    zgo.x += h4.z * rgo[4 * m + 2].x; zgo.y += h4.z * rgo[4 * m + 2].y;
                    zif.x += h4.w * rif[4 * m + 3].x; zif.y += h4.w * rif[4 * m + 3].y;
                    zgo.x += h4.w * rgo[4 * m + 3].x; zgo.y += h4.w * rgo[4 * m + 3].y;
                }
                float gi = 1.f / (1.f + __expf(-zif.x));
                float gf = 1.f / (1.f + __expf(-zif.y));
                float gg = 2.f / (1.f + __expf(-2.f * zgo.x)) - 1.f;
                float go = 1.f / (1.f + __expf(-zgo.y));
                c = gf * c + gi * gg;
                float h = go * (2.f / (1.f + __expf(-2.f * c)) - 1.f);
                h_all[(t + 1) * HSTRIDE + u] = h;
                // wave-sync: ensure the h write retired before next step's reads.
                // lgkmcnt(0) only (0xc07f) -- does NOT touch vmcnt, xk stays in flight.
                __builtin_amdgcn_s_waitcnt(0xc07f);
            }
        }
        __syncthreads();   // waves 1..3 waited here; h_all now visible to all

        // ---- G tail (all 256 threads): G[b*100+row][j] = h(row) . W1[:,j] ----
        const int brow0 = b * TT;
        for (int idx = tid; idx < TT * 13; idx += 256) {
            int row = idx / 13;
            int m = idx - row * 13;
            int j = 4 * m;
            const float* hrow = &h_all[(row + 1) * HSTRIDE];
            float ax = 0.f, ay = 0.f, az = 0.f, aw = 0.f;
#pragma unroll
            for (int u4 = 0; u4 < 16; ++u4) {
                float4 hv  = *(const float4*)&hrow[4 * u4];
                float4 w0  = *(const float4*)&w1s[(4 * u4 + 0) * 52 + j];
                float4 w1v = *(const float4*)&w1s[(4 * u4 + 1) * 52 + j];
                float4 w2  = *(const float4*)&w1s[(4 * u4 + 2) * 52 + j];
                float4 w3  = *(const float4*)&w1s[(4 * u4 + 3) * 52 + j];
                ax += hv.x * w0.x + hv.y * w1v.x + hv.z * w2.x + hv.w * w3.x;
                ay += hv.x * w0.y + hv.y * w1v.y + hv.z * w2.y + hv.w * w3.y;
                az += hv.x * w0.z + hv.y * w1v.z + hv.z * w2.z + hv.w * w3.z;
                aw += hv.x * w0.w + hv.y * w1v.w + hv.z * w2.w + hv.w * w3.w;
            }
            if (m == 12) { az = 0.f; aw = 0.f; }   // cols 50,51 = 0
            *(float4*)&G[(brow0 + row) * GROW + j] = make_float4(ax, ay, az, aw);
        }
    } else {
        // ---- k3: XcT[j][p] = b1[j] + sum_k X[p][k]*W1[64+k][j] ----
        float* Xs  = smem;          // [128][65]
        float* W1T = smem + 8320;   // [50][128]
        const int p0 = (blockIdx.x - 8) * 64;
        for (int idx = tid; idx < 6400; idx += 256) {
            int k = idx & 127, jj = idx >> 7;
            W1T[jj * 128 + k] = W1[(64 + k) * 50 + jj];
        }
#pragma unroll
        for (int r = 0; r < 8; ++r) {
            int flat = (tid + 256 * r) * 4;
            int i = flat >> 7;
            int k = flat & 127;
            int p = p0 + i;
            float4 v = make_float4(0.f, 0.f, 0.f, 0.f);
            if (p < PP) v = *(const float4*)&X[p * 128 + k];
            Xs[(k + 0) * 65 + i] = v.x;
            Xs[(k + 1) * 65 + i] = v.y;
            Xs[(k + 2) * 65 + i] = v.z;
            Xs[(k + 3) * 65 + i] = v.w;
        }
        __syncthreads();
        const int ploc = tid & 63;
        const int j0 = tid >> 6;
        float acc[13];
#pragma unroll
        for (int m = 0; m < 13; ++m) {
            int jj = j0 * 13 + m;
            acc[m] = (jj < 50) ? b1[jj] : 0.f;
        }
        for (int k4 = 0; k4 < 32; ++k4) {
            const int k = 4 * k4;
            float x0 = Xs[(k + 0) * 65 + ploc];
            float x1 = Xs[(k + 1) * 65 + ploc];
            float x2 = Xs[(k + 2) * 65 + ploc];
            float x3 = Xs[(k + 3) * 65 + ploc];
#pragma unroll
            for (int m = 0; m < 13; ++m) {
                int jj = j0 * 13 + m;
                if (jj < 50) {
                    float4 w = *(const float4*)&W1T[jj * 128 + k];
                    acc[m] += x0 * w.x + x1 * w.y + x2 * w.z + x3 * w.w;
                }
            }
        }
        int p = p0 + ploc;
        if (p < PP) {
#pragma unroll
            for (int m = 0; m < 13; ++m) {
                int jj = j0 * 13 + m;
                if (jj < 50) XcT[jj * PP + p] = acc[m];
            }
        }
        for (int idx = tid; idx < 6 * 64; idx += 256) {
            int r = 50 + (idx >> 6);
            int pp = p0 + (idx & 63);
            if (pp < PP) XcT[r * PP + pp] = 0.f;
        }
    }
}

// ---------------- K4: suffix-accumulate V[p,j] += a[s,p]*Gs[s,j]; emit per t-chunk -----
// (unchanged from round 6 -- it dropped out of the top-5; preserve the signal)
__global__ __launch_bounds__(256) void k4_main(const int* __restrict__ pro_id,
    const float* __restrict__ cos_X, const float* __restrict__ XcT,
    const float* __restrict__ G, const float* __restrict__ W2,
    const float* __restrict__ b2, float* __restrict__ out)
{
    __shared__ __align__(16) float Gs[TT * GROW];  // 22.4 KB
    __shared__ float w2s[NJ];
    __shared__ int spid[TT];
    const int b = blockIdx.z;
    const int p = blockIdx.y * 256 + threadIdx.x;
    const int ci = blockIdx.x;
    const int t0 = ci * 7;
    const int t1 = (t0 + 7 < TT) ? (t0 + 7) : TT;
    const bool valid = p < PP;
    const int pc = valid ? p : 0;
    const int tid = threadIdx.x;

    {
        const float4* Gg = (const float4*)(G + b * TT * GROW);
        float4* Gd = (float4*)Gs;
        for (int idx = tid; idx < TT * GROW / 4; idx += 256) Gd[idx] = Gg[idx];
        if (tid < TT) spid[tid] = pro_id[b * TT + tid];
        if (tid < NJ) w2s[tid] = (tid < 50) ? W2[tid] : 0.f;
    }

    float V[NJ];
#pragma unroll
    for (int jj = 0; jj < NJ; ++jj) V[jj] = XcT[jj * PP + pc];
    const float b2v = b2[0];
    __syncthreads();

    const float* cb = cos_X + pc;
    float a0 = cb[spid[99] * PP];
    float a1 = cb[spid[98] * PP];
    float a2 = cb[spid[97] * PP];
    float a3 = cb[spid[96] * PP];

    for (int s = TT - 1; s >= t0; --s) {
        float a = a0; a0 = a1; a1 = a2; a2 = a3;
        int sp = s - 4;
        if (sp < t0) sp = t0;
        a3 = cb[spid[sp] * PP];
        const float4* G4 = (const float4*)&Gs[s * GROW];
#pragma unroll
        for (int jv = 0; jv < 13; ++jv) {
            float4 gv = G4[jv];
            V[4 * jv + 0] += a * gv.x;
            V[4 * jv + 1] += a * gv.y;
            V[4 * jv + 2] += a * gv.z;
            V[4 * jv + 3] += a * gv.w;
        }
        if (s < t1) {
            float acc = b2v;
#pragma unroll
            for (int jv = 0; jv < 13; ++jv) {
                float4 wv = *(const float4*)&w2s[4 * jv];
                acc += wv.x * fmaxf(V[4 * jv + 0], 0.f)
                     + wv.y * fmaxf(V[4 * jv + 1], 0.f)
                     + wv.z * fmaxf(V[4 * jv + 2], 0.f)
                     + wv.w * fmaxf(V[4 * jv + 3], 0.f);
            }
            if (valid) out[(b * TT + s) * PP + p] = acc;
        }
    }
}

extern "C" void kernel_launch(void* const* d_in, const int* in_sizes, int n_in,
                              void* d_out, int out_size, void* d_ws, size_t ws_size,
                              hipStream_t stream)
{
    const int* pro_id  = (const int*)d_in[0];
    const int* label   = (const int*)d_in[1];
    const float* X     = (const float*)d_in[3];
    const float* cos_X = (const float*)d_in[4];
    // d_in[5] trimatrix: structurally tril(ones) — suffix-sum semantics hardcoded
    const float* onehot = (const float*)d_in[6];
    const float* lk    = (const float*)d_in[7];
    const float* lr    = (const float*)d_in[8];
    const float* lb    = (const float*)d_in[9];
    const float* W1    = (const float*)d_in[10];
    const float* b1    = (const float*)d_in[11];
    const float* W2    = (const float*)d_in[12];
    const float* b2    = (const float*)d_in[13];

    float* ws  = (float*)d_ws;
    float* xk  = ws;            // 204800
    float* XcT = ws + 204800;   // 56000
    float* G   = ws + 260800;   // 44800
    float* out = (float*)d_out;

    hipLaunchKernelGGL(k1_xk,  dim3(400),      dim3(256), 0, stream,
                       pro_id, label, X, onehot, lk, lb, xk);
    hipLaunchKernelGGL(mid,    dim3(24),       dim3(256), 0, stream,
                       xk, lr, W1, X, b1, G, XcT);
    hipLaunchKernelGGL(k4_main,dim3(15, 4, 8), dim3(256), 0, stream,
                       pro_id, cos_X, XcT, G, W2, b2, out);
}

// Round 8
// 210.017 us; speedup vs baseline: 1.2536x; 1.2536x over previous
//
#include <hip/hip_runtime.h>
#include <math.h>

#define BB 8
#define TT 100
#define PP 1000
#define NJ 52      // V regs per thread in k4 (50 real j, 2 pad)
#define GROW 56    // G row stride floats (224B, 16B aligned)
#define HSTRIDE 68 // h_all row stride floats (272B, 16B aligned)

// ws layout (floats):
//   xk : [800][256] at 0        (204800)
//   XcT: [56][1000] at 204800   (56000)
//   G  : [800][56]  at 260800   (44800)

// ---------------- K1: xk[bt][j] = bias[j] + sum_k xt[bt][k]*kern[k][j] -----------------
__global__ __launch_bounds__(256) void k1_xk(const int* __restrict__ pro_id,
    const int* __restrict__ label, const float* __restrict__ X,
    const float* __restrict__ onehot, const float* __restrict__ kern,
    const float* __restrict__ bias, float* __restrict__ xk)
{
    __shared__ __align__(16) float xt[2][256];
    const int j = threadIdx.x;
    const int r0 = blockIdx.x * 2;
#pragma unroll
    for (int r = 0; r < 2; ++r) {
        int pid = pro_id[r0 + r];
        int lab = label[r0 + r];
        xt[r][j] = X[pid * 128 + (j & 127)] * onehot[lab * 256 + j];
    }
    __syncthreads();
    float acc0 = bias[j], acc1 = acc0;
    float kc[8];
#pragma unroll
    for (int i = 0; i < 8; ++i) kc[i] = kern[i * 256 + j];
    for (int kg = 0; kg < 32; ++kg) {
        float kn[8];
        const int kgn = (kg < 31) ? kg + 1 : 31;
#pragma unroll
        for (int i = 0; i < 8; ++i) kn[i] = kern[(kgn * 8 + i) * 256 + j];
        const int k0 = kg * 8;
        float4 xa0 = *(const float4*)&xt[0][k0];
        float4 xa1 = *(const float4*)&xt[0][k0 + 4];
        float4 xb0 = *(const float4*)&xt[1][k0];
        float4 xb1 = *(const float4*)&xt[1][k0 + 4];
        acc0 += xa0.x * kc[0] + xa0.y * kc[1] + xa0.z * kc[2] + xa0.w * kc[3]
              + xa1.x * kc[4] + xa1.y * kc[5] + xa1.z * kc[6] + xa1.w * kc[7];
        acc1 += xb0.x * kc[0] + xb0.y * kc[1] + xb0.z * kc[2] + xb0.w * kc[3]
              + xb1.x * kc[4] + xb1.y * kc[5] + xb1.z * kc[6] + xb1.w * kc[7];
#pragma unroll
        for (int i = 0; i < 8; ++i) kc[i] = kn[i];
    }
    xk[(r0 + 0) * 256 + j] = acc0;
    xk[(r0 + 1) * 256 + j] = acc1;
}

// ---------------- MID: blocks 0..7 = LSTM, blocks 8..23 = XcT (k3) ---------------------
// LSTM v4: 4-wave gate-interleaved layout (round 6) + ALL 100 xk values preloaded
// into a VGPR array (~190 VGPR total, fits 256 arch limit -- round 7's 1-wave
// version needed 280+ and spilled). t-loop fully unrolled so xreg[] stays in regs.
// Loop body has ZERO global loads -> the per-step barrier's vmcnt(0) drain is free
// (round 6 paid ~900 cyc/step draining the xk prefetch).
__global__ __launch_bounds__(256, 1) void mid(const float* __restrict__ xk,
    const float* __restrict__ rec, const float* __restrict__ W1,
    const float* __restrict__ X, const float* __restrict__ b1,
    float* __restrict__ G, float* __restrict__ XcT)
{
    __shared__ __align__(16) float smem[14720];  // 58.9 KB union
    const int tid = threadIdx.x;

    if (blockIdx.x < 8) {
        float* h_all = smem;                      // [101][68] = 27.5 KB
        float* w1s   = smem + (TT + 1) * HSTRIDE; // [64][52]  = 13.3 KB
        const int b = blockIdx.x;
        const int l = tid & 63;
        const int w = tid >> 6;
        const int u = (w << 4) | (l & 15);
        const int g = l >> 4;
        const int col = (g << 6) | u;

        for (int idx = tid; idx < 3200; idx += 256) {
            int u2 = idx / 50, jj = idx - u2 * 50;
            w1s[u2 * 52 + jj] = W1[idx];
        }
        float rcol[64];
#pragma unroll
        for (int u2 = 0; u2 < 64; ++u2) rcol[u2] = rec[u2 * 256 + col];

        // preload this column's xk for ALL timesteps into VGPRs (one-time latency)
        const float* xkb = xk + b * TT * 256;
        float xreg[TT];
#pragma unroll
        for (int t = 0; t < TT; ++t) xreg[t] = xkb[t * 256 + col];

        if (tid < 64) h_all[tid] = 0.f;           // h(-1) = 0
        float c = 0.f;
        __syncthreads();

#pragma unroll
        for (int t = 0; t < TT; ++t) {
            float a0 = xreg[t], a1 = 0.f, a2 = 0.f, a3 = 0.f;
            const float4* h4p = (const float4*)&h_all[t * HSTRIDE];
#pragma unroll
            for (int m = 0; m < 16; ++m) {
                float4 hv = h4p[m];               // broadcast ds_read_b128
                a0 += hv.x * rcol[4 * m + 0];
                a1 += hv.y * rcol[4 * m + 1];
                a2 += hv.z * rcol[4 * m + 2];
                a3 += hv.w * rcol[4 * m + 3];
            }
            float z = (a0 + a1) + (a2 + a3);
            float act;
            if (g == 2) act = 2.f / (1.f + __expf(-2.f * z)) - 1.f;   // tanh gate
            else        act = 1.f / (1.f + __expf(-z));
            const int base = l & 15;
            float gi = __shfl(act, base);
            float gf = __shfl(act, base + 16);
            float gg = __shfl(act, base + 32);
            float go = __shfl(act, base + 48);
            c = gf * c + gi * gg;
            float h = go * (2.f / (1.f + __expf(-2.f * c)) - 1.f);
            if (g == 0) h_all[(t + 1) * HSTRIDE + u] = h;
            __syncthreads();                      // drains nothing: no VMEM in loop
        }

        // ---- G tail (all 256 threads): G[b*100+row][j] = h(row) . W1[:,j] ----
        const int brow0 = b * TT;
        for (int idx = tid; idx < TT * 13; idx += 256) {
            int row = idx / 13;
            int m = idx - row * 13;
            int j = 4 * m;
            const float* hrow = &h_all[(row + 1) * HSTRIDE];
            float ax = 0.f, ay = 0.f, az = 0.f, aw = 0.f;
#pragma unroll
            for (int u4 = 0; u4 < 16; ++u4) {
                float4 hv  = *(const float4*)&hrow[4 * u4];
                float4 w0  = *(const float4*)&w1s[(4 * u4 + 0) * 52 + j];
                float4 w1v = *(const float4*)&w1s[(4 * u4 + 1) * 52 + j];
                float4 w2  = *(const float4*)&w1s[(4 * u4 + 2) * 52 + j];
                float4 w3  = *(const float4*)&w1s[(4 * u4 + 3) * 52 + j];
                ax += hv.x * w0.x + hv.y * w1v.x + hv.z * w2.x + hv.w * w3.x;
                ay += hv.x * w0.y + hv.y * w1v.y + hv.z * w2.y + hv.w * w3.y;
                az += hv.x * w0.z + hv.y * w1v.z + hv.z * w2.z + hv.w * w3.z;
                aw += hv.x * w0.w + hv.y * w1v.w + hv.z * w2.w + hv.w * w3.w;
            }
            if (m == 12) { az = 0.f; aw = 0.f; }   // cols 50,51 = 0
            *(float4*)&G[(brow0 + row) * GROW + j] = make_float4(ax, ay, az, aw);
        }
    } else {
        // ---- k3: XcT[j][p] = b1[j] + sum_k X[p][k]*W1[64+k][j] ----
        float* Xs  = smem;          // [128][65]
        float* W1T = smem + 8320;   // [50][128]
        const int p0 = (blockIdx.x - 8) * 64;
        for (int idx = tid; idx < 6400; idx += 256) {
            int k = idx & 127, jj = idx >> 7;
            W1T[jj * 128 + k] = W1[(64 + k) * 50 + jj];
        }
#pragma unroll
        for (int r = 0; r < 8; ++r) {
            int flat = (tid + 256 * r) * 4;
            int i = flat >> 7;
            int k = flat & 127;
            int p = p0 + i;
            float4 v = make_float4(0.f, 0.f, 0.f, 0.f);
            if (p < PP) v = *(const float4*)&X[p * 128 + k];
            Xs[(k + 0) * 65 + i] = v.x;
            Xs[(k + 1) * 65 + i] = v.y;
            Xs[(k + 2) * 65 + i] = v.z;
            Xs[(k + 3) * 65 + i] = v.w;
        }
        __syncthreads();
        const int ploc = tid & 63;
        const int j0 = tid >> 6;
        float acc[13];
#pragma unroll
        for (int m = 0; m < 13; ++m) {
            int jj = j0 * 13 + m;
            acc[m] = (jj < 50) ? b1[jj] : 0.f;
        }
        for (int k4 = 0; k4 < 32; ++k4) {
            const int k = 4 * k4;
            float x0 = Xs[(k + 0) * 65 + ploc];
            float x1 = Xs[(k + 1) * 65 + ploc];
            float x2 = Xs[(k + 2) * 65 + ploc];
            float x3 = Xs[(k + 3) * 65 + ploc];
#pragma unroll
            for (int m = 0; m < 13; ++m) {
                int jj = j0 * 13 + m;
                if (jj < 50) {
                    float4 wv = *(const float4*)&W1T[jj * 128 + k];
                    acc[m] += x0 * wv.x + x1 * wv.y + x2 * wv.z + x3 * wv.w;
                }
            }
        }
        int p = p0 + ploc;
        if (p < PP) {
#pragma unroll
            for (int m = 0; m < 13; ++m) {
                int jj = j0 * 13 + m;
                if (jj < 50) XcT[jj * PP + p] = acc[m];
            }
        }
        for (int idx = tid; idx < 6 * 64; idx += 256) {
            int r = 50 + (idx >> 6);
            int pp = p0 + (idx & 63);
            if (pp < PP) XcT[r * PP + pp] = 0.f;
        }
    }
}

// ---------------- K4: suffix-accumulate V[p,j] += a[s,p]*Gs[s,j]; emit per t-chunk -----
__global__ __launch_bounds__(256) void k4_main(const int* __restrict__ pro_id,
    const float* __restrict__ cos_X, const float* __restrict__ XcT,
    const float* __restrict__ G, const float* __restrict__ W2,
    const float* __restrict__ b2, float* __restrict__ out)
{
    __shared__ __align__(16) float Gs[TT * GROW];  // 22.4 KB
    __shared__ float w2s[NJ];
    __shared__ int spid[TT];
    const int b = blockIdx.z;
    const int p = blockIdx.y * 256 + threadIdx.x;
    const int ci = blockIdx.x;
    const int t0 = ci * 7;
    const int t1 = (t0 + 7 < TT) ? (t0 + 7) : TT;
    const bool valid = p < PP;
    const int pc = valid ? p : 0;
    const int tid = threadIdx.x;

    {
        const float4* Gg = (const float4*)(G + b * TT * GROW);
        float4* Gd = (float4*)Gs;
        for (int idx = tid; idx < TT * GROW / 4; idx += 256) Gd[idx] = Gg[idx];
        if (tid < TT) spid[tid] = pro_id[b * TT + tid];
        if (tid < NJ) w2s[tid] = (tid < 50) ? W2[tid] : 0.f;
    }

    float V[NJ];
#pragma unroll
    for (int jj = 0; jj < NJ; ++jj) V[jj] = XcT[jj * PP + pc];
    const float b2v = b2[0];
    __syncthreads();

    const float* cb = cos_X + pc;
    float a0 = cb[spid[99] * PP];
    float a1 = cb[spid[98] * PP];
    float a2 = cb[spid[97] * PP];
    float a3 = cb[spid[96] * PP];

    for (int s = TT - 1; s >= t0; --s) {
        float a = a0; a0 = a1; a1 = a2; a2 = a3;
        int sp = s - 4;
        if (sp < t0) sp = t0;
        a3 = cb[spid[sp] * PP];
        const float4* G4 = (const float4*)&Gs[s * GROW];
#pragma unroll
        for (int jv = 0; jv < 13; ++jv) {
            float4 gv = G4[jv];
            V[4 * jv + 0] += a * gv.x;
            V[4 * jv + 1] += a * gv.y;
            V[4 * jv + 2] += a * gv.z;
            V[4 * jv + 3] += a * gv.w;
        }
        if (s < t1) {
            float acc = b2v;
#pragma unroll
            for (int jv = 0; jv < 13; ++jv) {
                float4 wv = *(const float4*)&w2s[4 * jv];
                acc += wv.x * fmaxf(V[4 * jv + 0], 0.f)
                     + wv.y * fmaxf(V[4 * jv + 1], 0.f)
                     + wv.z * fmaxf(V[4 * jv + 2], 0.f)
                     + wv.w * fmaxf(V[4 * jv + 3], 0.f);
            }
            if (valid) out[(b * TT + s) * PP + p] = acc;
        }
    }
}

extern "C" void kernel_launch(void* const* d_in, const int* in_sizes, int n_in,
                              void* d_out, int out_size, void* d_ws, size_t ws_size,
                              hipStream_t stream)
{
    const int* pro_id  = (const int*)d_in[0];
    const int* label   = (const int*)d_in[1];
    const float* X     = (const float*)d_in[3];
    const float* cos_X = (const float*)d_in[4];
    // d_in[5] trimatrix: structurally tril(ones) — suffix-sum semantics hardcoded
    const float* onehot = (const float*)d_in[6];
    const float* lk    = (const float*)d_in[7];
    const float* lr    = (const float*)d_in[8];
    const float* lb    = (const float*)d_in[9];
    const float* W1    = (const float*)d_in[10];
    const float* b1    = (const float*)d_in[11];
    const float* W2    = (const float*)d_in[12];
    const float* b2    = (const float*)d_in[13];

    float* ws  = (float*)d_ws;
    float* xk  = ws;            // 204800
    float* XcT = ws + 204800;   // 56000
    float* G   = ws + 260800;   // 44800
    float* out = (float*)d_out;

    hipLaunchKernelGGL(k1_xk,  dim3(400),      dim3(256), 0, stream,
                       pro_id, label, X, onehot, lk, lb, xk);
    hipLaunchKernelGGL(mid,    dim3(24),       dim3(256), 0, stream,
                       xk, lr, W1, X, b1, G, XcT);
    hipLaunchKernelGGL(k4_main,dim3(15, 4, 8), dim3(256), 0, stream,
                       pro_id, cos_X, XcT, G, W2, b2, out);
}

// Round 9
// 208.378 us; speedup vs baseline: 1.2635x; 1.0079x over previous
//
#include <hip/hip_runtime.h>
#include <math.h>

#define BB 8
#define TT 100
#define PP 1000
#define NJ 52      // V regs per thread in k4 (50 real j, 2 pad)
#define GROW 56    // G row stride floats (224B, 16B aligned)
#define HSTRIDE 68 // h_all row stride floats (272B, 16B aligned)

// ws layout (floats):
//   xk : [800][256] at 0        (204800)
//   XcT: [56][1000] at 204800   (56000)
//   G  : [800][56]  at 260800   (44800)

// Raw workgroup barrier: lgkmcnt(0) (LDS/shfl visibility) + s_barrier, but NO
// vmcnt drain -- __syncthreads() emits s_waitcnt vmcnt(0) which force-drains
// in-flight global prefetches every step (round-6: ~900 cyc/step; round-8:
// xreg[] spill to scratch, +800KB FETCH/WRITE). This keeps xk loads in flight.
#define WAVE_BARRIER() asm volatile("s_waitcnt lgkmcnt(0)\ns_barrier" ::: "memory")

// ---------------- K1: xk[bt][j] = bias[j] + sum_k xt[bt][k]*kern[k][j] -----------------
__global__ __launch_bounds__(256) void k1_xk(const int* __restrict__ pro_id,
    const int* __restrict__ label, const float* __restrict__ X,
    const float* __restrict__ onehot, const float* __restrict__ kern,
    const float* __restrict__ bias, float* __restrict__ xk)
{
    __shared__ __align__(16) float xt[2][256];
    const int j = threadIdx.x;
    const int r0 = blockIdx.x * 2;
#pragma unroll
    for (int r = 0; r < 2; ++r) {
        int pid = pro_id[r0 + r];
        int lab = label[r0 + r];
        xt[r][j] = X[pid * 128 + (j & 127)] * onehot[lab * 256 + j];
    }
    __syncthreads();
    float acc0 = bias[j], acc1 = acc0;
    float kc[8];
#pragma unroll
    for (int i = 0; i < 8; ++i) kc[i] = kern[i * 256 + j];
    for (int kg = 0; kg < 32; ++kg) {
        float kn[8];
        const int kgn = (kg < 31) ? kg + 1 : 31;
#pragma unroll
        for (int i = 0; i < 8; ++i) kn[i] = kern[(kgn * 8 + i) * 256 + j];
        const int k0 = kg * 8;
        float4 xa0 = *(const float4*)&xt[0][k0];
        float4 xa1 = *(const float4*)&xt[0][k0 + 4];
        float4 xb0 = *(const float4*)&xt[1][k0];
        float4 xb1 = *(const float4*)&xt[1][k0 + 4];
        acc0 += xa0.x * kc[0] + xa0.y * kc[1] + xa0.z * kc[2] + xa0.w * kc[3]
              + xa1.x * kc[4] + xa1.y * kc[5] + xa1.z * kc[6] + xa1.w * kc[7];
        acc1 += xb0.x * kc[0] + xb0.y * kc[1] + xb0.z * kc[2] + xb0.w * kc[3]
              + xb1.x * kc[4] + xb1.y * kc[5] + xb1.z * kc[6] + xb1.w * kc[7];
#pragma unroll
        for (int i = 0; i < 8; ++i) kc[i] = kn[i];
    }
    xk[(r0 + 0) * 256 + j] = acc0;
    xk[(r0 + 1) * 256 + j] = acc1;
}

// ---------------- MID: blocks 0..7 = LSTM, blocks 8..23 = XcT (k3) ---------------------
// LSTM v5: round-6 4-wave gate-interleaved layout (rec = 64 VGPR/thread, no spill)
// + depth-3 xk register pipeline + WAVE_BARRIER() instead of __syncthreads in the
// recurrence. The xk prefetch now survives across steps (no vmcnt drain).
__global__ __launch_bounds__(256, 1) void mid(const float* __restrict__ xk,
    const float* __restrict__ rec, const float* __restrict__ W1,
    const float* __restrict__ X, const float* __restrict__ b1,
    float* __restrict__ G, float* __restrict__ XcT)
{
    __shared__ __align__(16) float smem[14720];  // 58.9 KB union
    const int tid = threadIdx.x;

    if (blockIdx.x < 8) {
        float* h_all = smem;                      // [101][68] = 27.5 KB
        float* w1s   = smem + (TT + 1) * HSTRIDE; // [64][52]  = 13.3 KB
        const int b = blockIdx.x;
        const int l = tid & 63;
        const int w = tid >> 6;
        const int u = (w << 4) | (l & 15);
        const int g = l >> 4;
        const int col = (g << 6) | u;

        for (int idx = tid; idx < 3200; idx += 256) {
            int u2 = idx / 50, jj = idx - u2 * 50;
            w1s[u2 * 52 + jj] = W1[idx];
        }
        float rcol[64];
#pragma unroll
        for (int u2 = 0; u2 < 64; ++u2) rcol[u2] = rec[u2 * 256 + col];

        if (tid < 64) h_all[tid] = 0.f;           // h(-1) = 0
        float c = 0.f;
        const float* xkb = xk + b * TT * 256;
        // depth-3 pipeline; drained ONCE by the full barrier below, then kept
        // in flight for the whole loop (WAVE_BARRIER never touches vmcnt)
        float zc0 = xkb[col];
        float zc1 = xkb[256 + col];
        float zc2 = xkb[512 + col];
        __syncthreads();

        for (int t = 0; t < TT; ++t) {
            float a0 = zc0, a1 = 0.f, a2 = 0.f, a3 = 0.f;
            zc0 = zc1; zc1 = zc2;
            int tn = (t + 3 < TT) ? t + 3 : TT - 1;
            zc2 = xkb[tn * 256 + col];            // stays in flight ~3 steps
            const float4* h4p = (const float4*)&h_all[t * HSTRIDE];
#pragma unroll
            for (int m = 0; m < 16; ++m) {
                float4 hv = h4p[m];               // broadcast ds_read_b128
                a0 += hv.x * rcol[4 * m + 0];
                a1 += hv.y * rcol[4 * m + 1];
                a2 += hv.z * rcol[4 * m + 2];
                a3 += hv.w * rcol[4 * m + 3];
            }
            float z = (a0 + a1) + (a2 + a3);
            float act;
            if (g == 2) act = 2.f / (1.f + __expf(-2.f * z)) - 1.f;   // tanh gate
            else        act = 1.f / (1.f + __expf(-z));
            const int base = l & 15;
            float gi = __shfl(act, base);
            float gf = __shfl(act, base + 16);
            float gg = __shfl(act, base + 32);
            float go = __shfl(act, base + 48);
            c = gf * c + gi * gg;
            float h = go * (2.f / (1.f + __expf(-2.f * c)) - 1.f);
            if (g == 0) h_all[(t + 1) * HSTRIDE + u] = h;
            WAVE_BARRIER();                       // lgkmcnt(0)+s_barrier, NO vmcnt
        }
        __syncthreads();                          // one full fence before the tail

        // ---- G tail (all 256 threads): G[b*100+row][j] = h(row) . W1[:,j] ----
        const int brow0 = b * TT;
        for (int idx = tid; idx < TT * 13; idx += 256) {
            int row = idx / 13;
            int m = idx - row * 13;
            int j = 4 * m;
            const float* hrow = &h_all[(row + 1) * HSTRIDE];
            float ax = 0.f, ay = 0.f, az = 0.f, aw = 0.f;
#pragma unroll
            for (int u4 = 0; u4 < 16; ++u4) {
                float4 hv  = *(const float4*)&hrow[4 * u4];
                float4 w0  = *(const float4*)&w1s[(4 * u4 + 0) * 52 + j];
                float4 w1v = *(const float4*)&w1s[(4 * u4 + 1) * 52 + j];
                float4 w2  = *(const float4*)&w1s[(4 * u4 + 2) * 52 + j];
                float4 w3  = *(const float4*)&w1s[(4 * u4 + 3) * 52 + j];
                ax += hv.x * w0.x + hv.y * w1v.x + hv.z * w2.x + hv.w * w3.x;
                ay += hv.x * w0.y + hv.y * w1v.y + hv.z * w2.y + hv.w * w3.y;
                az += hv.x * w0.z + hv.y * w1v.z + hv.z * w2.z + hv.w * w3.z;
                aw += hv.x * w0.w + hv.y * w1v.w + hv.z * w2.w + hv.w * w3.w;
            }
            if (m == 12) { az = 0.f; aw = 0.f; }   // cols 50,51 = 0
            *(float4*)&G[(brow0 + row) * GROW + j] = make_float4(ax, ay, az, aw);
        }
    } else {
        // ---- k3: XcT[j][p] = b1[j] + sum_k X[p][k]*W1[64+k][j] ----
        float* Xs  = smem;          // [128][65]
        float* W1T = smem + 8320;   // [50][128]
        const int p0 = (blockIdx.x - 8) * 64;
        for (int idx = tid; idx < 6400; idx += 256) {
            int k = idx & 127, jj = idx >> 7;
            W1T[jj * 128 + k] = W1[(64 + k) * 50 + jj];
        }
#pragma unroll
        for (int r = 0; r < 8; ++r) {
            int flat = (tid + 256 * r) * 4;
            int i = flat >> 7;
            int k = flat & 127;
            int p = p0 + i;
            float4 v = make_float4(0.f, 0.f, 0.f, 0.f);
            if (p < PP) v = *(const float4*)&X[p * 128 + k];
            Xs[(k + 0) * 65 + i] = v.x;
            Xs[(k + 1) * 65 + i] = v.y;
            Xs[(k + 2) * 65 + i] = v.z;
            Xs[(k + 3) * 65 + i] = v.w;
        }
        __syncthreads();
        const int ploc = tid & 63;
        const int j0 = tid >> 6;
        float acc[13];
#pragma unroll
        for (int m = 0; m < 13; ++m) {
            int jj = j0 * 13 + m;
            acc[m] = (jj < 50) ? b1[jj] : 0.f;
        }
        for (int k4 = 0; k4 < 32; ++k4) {
            const int k = 4 * k4;
            float x0 = Xs[(k + 0) * 65 + ploc];
            float x1 = Xs[(k + 1) * 65 + ploc];
            float x2 = Xs[(k + 2) * 65 + ploc];
            float x3 = Xs[(k + 3) * 65 + ploc];
#pragma unroll
            for (int m = 0; m < 13; ++m) {
                int jj = j0 * 13 + m;
                if (jj < 50) {
                    float4 wv = *(const float4*)&W1T[jj * 128 + k];
                    acc[m] += x0 * wv.x + x1 * wv.y + x2 * wv.z + x3 * wv.w;
                }
            }
        }
        int p = p0 + ploc;
        if (p < PP) {
#pragma unroll
            for (int m = 0; m < 13; ++m) {
                int jj = j0 * 13 + m;
                if (jj < 50) XcT[jj * PP + p] = acc[m];
            }
        }
        for (int idx = tid; idx < 6 * 64; idx += 256) {
            int r = 50 + (idx >> 6);
            int pp = p0 + (idx & 63);
            if (pp < PP) XcT[r * PP + pp] = 0.f;
        }
    }
}

// ---------------- K4: suffix-accumulate V[p,j] += a[s,p]*Gs[s,j]; emit per t-chunk -----
__global__ __launch_bounds__(256) void k4_main(const int* __restrict__ pro_id,
    const float* __restrict__ cos_X, const float* __restrict__ XcT,
    const float* __restrict__ G, const float* __restrict__ W2,
    const float* __restrict__ b2, float* __restrict__ out)
{
    __shared__ __align__(16) float Gs[TT * GROW];  // 22.4 KB
    __shared__ float w2s[NJ];
    __shared__ int spid[TT];
    const int b = blockIdx.z;
    const int p = blockIdx.y * 256 + threadIdx.x;
    const int ci = blockIdx.x;
    const int t0 = ci * 7;
    const int t1 = (t0 + 7 < TT) ? (t0 + 7) : TT;
    const bool valid = p < PP;
    const int pc = valid ? p : 0;
    const int tid = threadIdx.x;

    {
        const float4* Gg = (const float4*)(G + b * TT * GROW);
        float4* Gd = (float4*)Gs;
        for (int idx = tid; idx < TT * GROW / 4; idx += 256) Gd[idx] = Gg[idx];
        if (tid < TT) spid[tid] = pro_id[b * TT + tid];
        if (tid < NJ) w2s[tid] = (tid < 50) ? W2[tid] : 0.f;
    }

    float V[NJ];
#pragma unroll
    for (int jj = 0; jj < NJ; ++jj) V[jj] = XcT[jj * PP + pc];
    const float b2v = b2[0];
    __syncthreads();

    const float* cb = cos_X + pc;
    float a0 = cb[spid[99] * PP];
    float a1 = cb[spid[98] * PP];
    float a2 = cb[spid[97] * PP];
    float a3 = cb[spid[96] * PP];

    for (int s = TT - 1; s >= t0; --s) {
        float a = a0; a0 = a1; a1 = a2; a2 = a3;
        int sp = s - 4;
        if (sp < t0) sp = t0;
        a3 = cb[spid[sp] * PP];
        const float4* G4 = (const float4*)&Gs[s * GROW];
#pragma unroll
        for (int jv = 0; jv < 13; ++jv) {
            float4 gv = G4[jv];
            V[4 * jv + 0] += a * gv.x;
            V[4 * jv + 1] += a * gv.y;
            V[4 * jv + 2] += a * gv.z;
            V[4 * jv + 3] += a * gv.w;
        }
        if (s < t1) {
            float acc = b2v;
#pragma unroll
            for (int jv = 0; jv < 13; ++jv) {
                float4 wv = *(const float4*)&w2s[4 * jv];
                acc += wv.x * fmaxf(V[4 * jv + 0], 0.f)
                     + wv.y * fmaxf(V[4 * jv + 1], 0.f)
                     + wv.z * fmaxf(V[4 * jv + 2], 0.f)
                     + wv.w * fmaxf(V[4 * jv + 3], 0.f);
            }
            if (valid) out[(b * TT + s) * PP + p] = acc;
        }
    }
}

extern "C" void kernel_launch(void* const* d_in, const int* in_sizes, int n_in,
                              void* d_out, int out_size, void* d_ws, size_t ws_size,
                              hipStream_t stream)
{
    const int* pro_id  = (const int*)d_in[0];
    const int* label   = (const int*)d_in[1];
    const float* X     = (const float*)d_in[3];
    const float* cos_X = (const float*)d_in[4];
    // d_in[5] trimatrix: structurally tril(ones) — suffix-sum semantics hardcoded
    const float* onehot = (const float*)d_in[6];
    const float* lk    = (const float*)d_in[7];
    const float* lr    = (const float*)d_in[8];
    const float* lb    = (const float*)d_in[9];
    const float* W1    = (const float*)d_in[10];
    const float* b1    = (const float*)d_in[11];
    const float* W2    = (const float*)d_in[12];
    const float* b2    = (const float*)d_in[13];

    float* ws  = (float*)d_ws;
    float* xk  = ws;            // 204800
    float* XcT = ws + 204800;   // 56000
    float* G   = ws + 260800;   // 44800
    float* out = (float*)d_out;

    hipLaunchKernelGGL(k1_xk,  dim3(400),      dim3(256), 0, stream,
                       pro_id, label, X, onehot, lk, lb, xk);
    hipLaunchKernelGGL(mid,    dim3(24),       dim3(256), 0, stream,
                       xk, lr, W1, X, b1, G, XcT);
    hipLaunchKernelGGL(k4_main,dim3(15, 4, 8), dim3(256), 0, stream,
                       pro_id, cos_X, XcT, G, W2, b2, out);
}